// Round 3
// baseline (8586.234 us; speedup 1.0000x reference)
//
#include <hip/hip_runtime.h>
#include <cfloat>

// Problem constants
#define B_SZ 32768
#define K_SZ 8192
#define D_SZ 512

static constexpr float DECAY = 0.99f;
static constexpr float OMD   = 1.0f - 0.99f;   // (1 - decay) in fp32
static constexpr float EPS   = 1e-5f;

// ---------------------------------------------------------------------------
// Kernel A: row sum-of-squares. One wave per row (D=512).
// ---------------------------------------------------------------------------
__global__ __launch_bounds__(256)
void rowsq_kernel(const float* __restrict__ src, float* __restrict__ dst) {
    const int wave = threadIdx.x >> 6;
    const int lane = threadIdx.x & 63;
    const int r = blockIdx.x * 4 + wave;
    const float* row = src + (size_t)r * D_SZ;
    float s = 0.f;
#pragma unroll
    for (int i = 0; i < 2; ++i) {
        float4 v = *reinterpret_cast<const float4*>(row + i * 256 + lane * 4);
        s += v.x * v.x + v.y * v.y + v.z * v.z + v.w * v.w;
    }
#pragma unroll
    for (int off = 32; off >= 1; off >>= 1) s += __shfl_xor(s, off);
    if (lane == 0) dst[r] = s;
}

// ---------------------------------------------------------------------------
// Kernel B: EMA init. o_nemcb = DECAY*ema_cb; o_ncs = DECAY*ema_cs.
// ---------------------------------------------------------------------------
__global__ __launch_bounds__(256)
void init_ema_kernel(const float* __restrict__ ema_cb,
                     const float* __restrict__ ema_cs,
                     float* __restrict__ o_nemcb,
                     float* __restrict__ o_ncs) {
    const size_t i = (size_t)blockIdx.x * 256 + threadIdx.x;  // float4 index
    float4 e = *reinterpret_cast<const float4*>(ema_cb + i * 4);
    e.x *= DECAY; e.y *= DECAY; e.z *= DECAY; e.w *= DECAY;
    *reinterpret_cast<float4*>(o_nemcb + i * 4) = e;
    if (i < K_SZ) o_ncs[i] = DECAY * ema_cs[i];
}

// ---------------------------------------------------------------------------
// Kernel 1: distance argmin.  R3 restructure.
//
// Grid: 256 row-blocks x 64 col-blocks; block 256 thr = 4 waves;
// tile 128x128, thread-tile 8x8 (tr = lane&15 rows; cols wid*32+(lane>>4)*8).
//
// LDS: row-major [row][32 d] per chunk, DOUBLE-buffered (2 x (16+16) KB =
// 64 KB), staged with __builtin_amdgcn_global_load_lds width=16 (no VGPR
// round-trip, zero ds_writes, zero staging VALU). 2-phase pipeline:
//   STAGE(next) ; compute(cur) ; __syncthreads()   -- 1 barrier/chunk.
//
// Swizzle (rule #21: linear LDS dest + inverse-permuted global src + XOR'd
// read). Logical (row, d4) lives at phys slot (row, d4 ^ s(row)),
// s(row) = (row ^ (row>>3)) & 7. bank-quad = phys only (row stride 128B).
//   a-reads (fixed r, 16 tr): phys = dq ^ ((r^tr)&7) -> 8 quads x 2 addrs
//     = 2-way = free.
//   b-reads (fixed r, 4 cg): phys = dq ^ ((r^(4wid+cg))&7) -> 4 distinct
//     quads, 16-lane broadcast = conflict-free.
//   gl_lds source: lane slot (row, phys) fetches global d4 = phys ^ s(row);
//     8 lanes/row stay inside one 128B segment -> coalescing unchanged.
// Read addr = base[r] ^ (dq<<4): base carries the axor bits (bits 4-6 of
// row*128 are zero) -> 1 v_xor per ds_read_b128.
//
// Accumulation: per acc[r][c], d ascends 0..511 exactly as all prior
// rounds (x,y,z,w within float4, dq ascending, chunks ascending) ->
// bit-identical scores -> identical indices.
// ---------------------------------------------------------------------------
typedef __attribute__((address_space(3))) void       lds_vp;
typedef const __attribute__((address_space(1))) void glb_vp;

__global__ __launch_bounds__(256, 2)
void argmin_kernel(const float* __restrict__ z_e,
                   const float* __restrict__ codebook,
                   const float* __restrict__ c_sq,
                   const float* __restrict__ z_sq,
                   float2* __restrict__ partials)   // [B][64]
{
    __shared__ float sm[2][2][128 * 32];   // [buf][z/c][row*32+phys*4] = 64 KB

    const int tid  = threadIdx.x;
    const int wid  = tid >> 6;
    const int lane = tid & 63;
    const int tr   = lane & 15;          // row group
    const int tr8  = tr * 8;
    const int cg   = lane >> 4;          // col group within wave
    const int c0l  = wid * 32 + cg * 8;  // local col base (0..120)

    const int rb = blockIdx.x >> 6;      // row block 0..255
    const int cb = blockIdx.x & 63;      // col block 0..63
    const int b0 = rb * 128;
    const int k0 = cb * 128;

    float acc[8][8];
#pragma unroll
    for (int r = 0; r < 8; ++r)
#pragma unroll
        for (int c = 0; c < 8; ++c) acc[r][c] = 0.f;

    // ---- Staging descriptors (hoisted; invariant across chunks) ----
    // slot = wid*256 + i*64 + lane; row = slot>>3; phys = slot&7;
    // source d4 = phys ^ s(row).  LDS dest: wave-uniform base + lane*16.
    const float* gz[4];
    const float* gc[4];
    int lwoff[4];                        // wave-uniform float offset
#pragma unroll
    for (int i = 0; i < 4; ++i) {
        const int slot = wid * 256 + i * 64 + lane;
        const int row  = slot >> 3;
        const int phys = slot & 7;
        const int ld4  = phys ^ ((row ^ (row >> 3)) & 7);
        gz[i] = z_e      + (size_t)(b0 + row) * D_SZ + ld4 * 4;
        gc[i] = codebook + (size_t)(k0 + row) * D_SZ + ld4 * 4;
        lwoff[i] = (wid * 256 + i * 64) * 4;
    }

    // ---- Reader byte-offset bases (XOR trick: bits 4-6 of row*128 = 0) ----
    int abase[8], bbase[8];
#pragma unroll
    for (int r = 0; r < 8; ++r) {
        abase[r] = (tr8 + r) * 128 + (((r ^ tr) & 7) << 4);
        bbase[r] = (c0l + r) * 128 + (((r ^ (4 * wid + cg)) & 7) << 4);
    }

#define STAGE(bf, dc)                                                         \
    {                                                                         \
        _Pragma("unroll")                                                     \
        for (int i = 0; i < 4; ++i) {                                         \
            __builtin_amdgcn_global_load_lds(                                 \
                (glb_vp*)(gz[i] + (dc)),                                      \
                (lds_vp*)(&sm[bf][0][0] + lwoff[i]), 16, 0, 0);               \
            __builtin_amdgcn_global_load_lds(                                 \
                (glb_vp*)(gc[i] + (dc)),                                      \
                (lds_vp*)(&sm[bf][1][0] + lwoff[i]), 16, 0, 0);               \
        }                                                                     \
    }

    STAGE(0, 0);
    __syncthreads();   // drains vmcnt -> buf0 ready

#pragma unroll 1
    for (int t = 0; t < 16; ++t) {
        const int cur = t & 1;
        if (t < 15) STAGE(cur ^ 1, (t + 1) * 32);   // prefetch next chunk

        const char* zb = reinterpret_cast<const char*>(&sm[cur][0][0]);
        const char* cbp = reinterpret_cast<const char*>(&sm[cur][1][0]);
#pragma unroll
        for (int dq = 0; dq < 8; ++dq) {
            float4 a4[8], b4[8];
#pragma unroll
            for (int r = 0; r < 8; ++r)
                a4[r] = *reinterpret_cast<const float4*>(zb + (abase[r] ^ (dq << 4)));
#pragma unroll
            for (int r = 0; r < 8; ++r)
                b4[r] = *reinterpret_cast<const float4*>(cbp + (bbase[r] ^ (dq << 4)));
#pragma unroll
            for (int r = 0; r < 8; ++r)
#pragma unroll
                for (int c = 0; c < 8; ++c) {
                    acc[r][c] = fmaf(a4[r].x, b4[c].x, acc[r][c]);
                    acc[r][c] = fmaf(a4[r].y, b4[c].y, acc[r][c]);
                    acc[r][c] = fmaf(a4[r].z, b4[c].z, acc[r][c]);
                    acc[r][c] = fmaf(a4[r].w, b4[c].w, acc[r][c]);
                }
        }
        __syncthreads();   // drain next-chunk loads + readers done with cur
    }
#undef STAGE

    // ---- Epilogue: d2 + per-row argmin over this block's 128 cols ----
    float zq[8], cq[8];
#pragma unroll
    for (int j = 0; j < 8; ++j) zq[j] = z_sq[b0 + tr8 + j];
#pragma unroll
    for (int j = 0; j < 8; ++j) cq[j] = c_sq[k0 + c0l + j];

    float mv[8];
    int   mi[8];
#pragma unroll
    for (int r = 0; r < 8; ++r) {
        mv[r] = FLT_MAX; mi[r] = 0;
#pragma unroll
        for (int c = 0; c < 8; ++c) {
            float s = fmaf(-2.f, acc[r][c], zq[r]) + cq[c];
            if (s < mv[r]) { mv[r] = s; mi[r] = k0 + c0l + c; }
        }
        // merge across the 4 col-groups of this wave (lanes tr, tr+16, +32, +48)
#pragma unroll
        for (int off = 16; off <= 32; off <<= 1) {
            float v2 = __shfl_xor(mv[r], off);
            int   i2 = __shfl_xor(mi[r], off);
            if (v2 < mv[r] || (v2 == mv[r] && i2 < mi[r])) { mv[r] = v2; mi[r] = i2; }
        }
    }

    // mbuf aliases the (now dead) staging LDS; last loop barrier protects it.
    float (*mbuf)[128][2] = reinterpret_cast<float (*)[128][2]>(&sm[0][0][0]);
    if (cg == 0) {
#pragma unroll
        for (int r = 0; r < 8; ++r) {
            mbuf[wid][tr8 + r][0] = mv[r];
            mbuf[wid][tr8 + r][1] = (float)mi[r];
        }
    }
    __syncthreads();
    // merge the 4 waves (ascending wid = ascending col -> first-min semantics)
    if (tid < 128) {
        float v = mbuf[0][tid][0];
        int   idx = (int)mbuf[0][tid][1];
#pragma unroll
        for (int w = 1; w < 4; ++w) {
            float v2 = mbuf[w][tid][0];
            int   i2 = (int)mbuf[w][tid][1];
            if (v2 < v || (v2 == v && i2 < idx)) { v = v2; idx = i2; }
        }
        partials[(size_t)(b0 + tid) * 64 + cb] = make_float2(v, (float)idx);
    }
}

// ---------------------------------------------------------------------------
// Kernel 1b: reduce 64 col-block partials per row -> final index.
// ---------------------------------------------------------------------------
__global__ __launch_bounds__(256)
void reduce_kernel(const float2* __restrict__ partials,
                   float* __restrict__ out_idx_f) {
    const int row  = blockIdx.x * 4 + (threadIdx.x >> 6);
    const int lane = threadIdx.x & 63;
    float2 p = partials[(size_t)row * 64 + lane];
    float v = p.x;
    int idx = (int)p.y;
#pragma unroll
    for (int off = 32; off >= 1; off >>= 1) {
        float v2 = __shfl_xor(v, off);
        int   i2 = __shfl_xor(idx, off);
        if (v2 < v || (v2 == v && i2 < idx)) { v = v2; idx = i2; }
    }
    if (lane == 0) out_idx_f[row] = (float)idx;
}

// ---------------------------------------------------------------------------
// Kernel 2: gather z_q + scatter EMA contributions into the outputs.
// ---------------------------------------------------------------------------
__global__ __launch_bounds__(256)
void scatter_kernel(const float* __restrict__ z_e,
                    const float* __restrict__ codebook,
                    const float* __restrict__ out_idx_f,
                    float* __restrict__ z_q,
                    float* __restrict__ o_ncs,
                    float* __restrict__ o_nemcb)
{
    const int wave = threadIdx.x >> 6;
    const int lane = threadIdx.x & 63;
    const int b = blockIdx.x * 4 + wave;
    const int idx = (int)out_idx_f[b];
#pragma unroll
    for (int i = 0; i < 2; ++i) {
        int d = i * 256 + lane * 4;
        float4 cq = *reinterpret_cast<const float4*>(
            codebook + (size_t)idx * D_SZ + d);
        *reinterpret_cast<float4*>(z_q + (size_t)b * D_SZ + d) = cq;
        float4 zv = *reinterpret_cast<const float4*>(
            z_e + (size_t)b * D_SZ + d);
        atomicAdd(o_nemcb + (size_t)idx * D_SZ + d + 0, OMD * zv.x);
        atomicAdd(o_nemcb + (size_t)idx * D_SZ + d + 1, OMD * zv.y);
        atomicAdd(o_nemcb + (size_t)idx * D_SZ + d + 2, OMD * zv.z);
        atomicAdd(o_nemcb + (size_t)idx * D_SZ + d + 3, OMD * zv.w);
    }
    if (lane == 0) atomicAdd(o_ncs + idx, OMD);
}

// ---------------------------------------------------------------------------
// Kernel 3: new_codebook = new_ema_codebook / (new_cluster_size + EPS).
// ---------------------------------------------------------------------------
__global__ __launch_bounds__(256)
void finalize_kernel(const float* __restrict__ o_nemcb,
                     const float* __restrict__ o_ncs,
                     float* __restrict__ o_ncb)
{
    const size_t i = (size_t)blockIdx.x * 256 + threadIdx.x;  // float4 index
    const int k = (int)(i >> 7);
    float4 nem = *reinterpret_cast<const float4*>(o_nemcb + i * 4);
    float den = o_ncs[k] + EPS;
    float4 ncb;
    ncb.x = nem.x / den; ncb.y = nem.y / den;
    ncb.z = nem.z / den; ncb.w = nem.w / den;
    *reinterpret_cast<float4*>(o_ncb + i * 4) = ncb;
}

// ---------------------------------------------------------------------------
extern "C" void kernel_launch(void* const* d_in, const int* in_sizes, int n_in,
                              void* d_out, int out_size, void* d_ws, size_t ws_size,
                              hipStream_t stream) {
    const float* z_e      = (const float*)d_in[0];   // (B, D)
    const float* codebook = (const float*)d_in[1];   // (K, D)
    const float* ema_cs   = (const float*)d_in[2];   // (K,)
    const float* ema_cb   = (const float*)d_in[3];   // (K, D)

    float* out = (float*)d_out;
    float* o_zq    = out;                                  // B*D
    float* o_idx   = out + (size_t)B_SZ * D_SZ;            // B
    float* o_ncb   = o_idx + B_SZ;                         // K*D
    float* o_ncs   = o_ncb + (size_t)K_SZ * D_SZ;          // K
    float* o_nemcb = o_ncs + K_SZ;                         // K*D

    // Scratch parked inside o_zq (overwritten by scatter_kernel afterwards).
    float2* w_part = (float2*)o_zq;
    float*  w_csq  = o_zq + (size_t)B_SZ * 64 * 2;
    float*  w_zsq  = w_csq + K_SZ;

    rowsq_kernel<<<K_SZ / 4, 256, 0, stream>>>(codebook, w_csq);
    rowsq_kernel<<<B_SZ / 4, 256, 0, stream>>>(z_e, w_zsq);
    init_ema_kernel<<<K_SZ * D_SZ / 4 / 256, 256, 0, stream>>>(
        ema_cb, ema_cs, o_nemcb, o_ncs);
    argmin_kernel<<<(B_SZ / 128) * (K_SZ / 128), 256, 0, stream>>>(
        z_e, codebook, w_csq, w_zsq, w_part);
    reduce_kernel<<<B_SZ / 4, 256, 0, stream>>>(w_part, o_idx);
    scatter_kernel<<<B_SZ / 4, 256, 0, stream>>>(z_e, codebook, o_idx,
                                                 o_zq, o_ncs, o_nemcb);
    finalize_kernel<<<K_SZ * D_SZ / 4 / 256, 256, 0, stream>>>(
        o_nemcb, o_ncs, o_ncb);
}